// Round 10
// baseline (408.247 us; speedup 1.0000x reference)
//
#include <hip/hip_runtime.h>
#include <hip/hip_bf16.h>

constexpr int kHD  = 10;
constexpr int kP   = 6;
constexpr int kH   = 128;
constexpr int kHin = 64;
constexpr float kScale = 63.0f / 127.0f;

__device__ __forceinline__ float sigm(float v) {
    return 1.0f / (1.0f + __expf(-v));
}

// Block = 768 threads = 12 waves = 6 parts x 128 px (one full output row of
// one image). Thread (p, px): p = tid>>7, px = tid&127. Wave-uniform part ->
// all weight reads are scalar loads. xp/xh/xf staged in LDS (exact footprint,
// no redundant cols); messages computed once per edge and exchanged via LDS.
__global__ __launch_bounds__(768, 4)
void Part_Graph_51539607552364_kernel(
    const float* __restrict__ xf,  const float* __restrict__ xh0,
    const float* __restrict__ xh1, const float* __restrict__ xp,
    const float* __restrict__ Wf,  const float* __restrict__ bfb,
    const float* __restrict__ Wh,  const float* __restrict__ bhb,
    const float* __restrict__ Watt, const float* __restrict__ batt,
    const float* __restrict__ Wdp, const float* __restrict__ Wup,
    float* __restrict__ out_xp,
    float* __restrict__ out_att)
{
    __shared__ float xpl[kP * kHD][kH];   // 30720 B  xp row tile
    __shared__ float xvl[2 * kHD][kHin];  //  5120 B  fy-blended xh source rows
    __shared__ float xfl[kHD][kHin];      //  2560 B  xf source row
    __shared__ float dpl[5][kHD][kH];     // 25600 B  edge messages
    __shared__ float dpal[kP][kH];        //  3072 B  dp_att       (total 67072)

    const int bid = blockIdx.x;
    const int n = bid >> 7;               // image
    const int y = bid & 127;              // output row

    int y0 = (int)((float)y * kScale); if (y0 > kHin - 2) y0 = kHin - 2;
    const float fy = (float)y * kScale - (float)y0;

    // ---- stage xp row: 60 planes x 128 cols ----
    for (int j = threadIdx.x; j < kP * kHD * kH; j += 768) {
        const int s = j >> 7, col = j & 127;
        xpl[s][col] = xp[((size_t)(n * kP * kHD + s) << 14) + y * kH + col];
    }
    // ---- stage xh rows y0,y0+1 blended by fy (block-uniform) ----
    for (int j = threadIdx.x; j < 2 * kHD * kHin; j += 768) {
        const int s = j >> 6, col = j & 63;          // s = map*10 + c
        const int m = s / kHD, c = s - m * kHD;
        const float* src = (m ? xh1 : xh0) +
                           ((size_t)((n * kHD + c) * kHin + y0) << 6) + col;
        const float r0 = src[0], r1 = src[kHin];
        xvl[s][col] = r0 + fy * (r1 - r0);
    }
    // ---- stage xf source row (y>>1) ----
    for (int j = threadIdx.x; j < kHD * kHin; j += 768) {
        const int c = j >> 6, col = j & 63;
        xfl[c][col] = xf[((size_t)((n * kHD + c) * kHin + (y >> 1)) << 6) + col];
    }
    __syncthreads();

    const int p  = threadIdx.x >> 7;      // part 0..5 (wave-uniform)
    const int px = threadIdx.x & 127;     // pixel in row

    // ---- per-thread inputs ----
    const float pxf_ = (float)px * kScale;
    int x0 = (int)pxf_; if (x0 > kHin - 2) x0 = kHin - 2;
    const float fx = pxf_ - (float)x0;
    const int m = (p >= 4) ? 1 : 0;

    float xpv[kHD], xhv[kHD], xfv[kHD];
    #pragma unroll
    for (int c = 0; c < kHD; ++c) {
        xpv[c] = xpl[p * kHD + c][px];
        const float* vr = &xvl[m * kHD + c][0];
        const float v0 = vr[x0], v1 = vr[x0 + 1];
        xhv[c] = v0 + fx * (v1 - v0);
        xfv[c] = xfl[c][px >> 1];
    }

    // ---- attentions (weights wave-uniform -> scalar loads) ----
    float af = bfb[p], ah = bhb[p], ad = batt[p];
    #pragma unroll
    for (int c = 0; c < kHD; ++c) {
        af += xfv[c] * Wf[p * 2 * kHD + c] + xpv[c] * Wf[p * 2 * kHD + kHD + c];
        ah += xhv[c] * Wh[p * 2 * kHD + c] + xpv[c] * Wh[p * 2 * kHD + kHD + c];
        ad += xpv[c] * Watt[p * kHD + c];
    }
    const float attf = sigm(af), atth = sigm(ah), dpa = sigm(ad);
    dpal[p][px] = dpa;
    out_att[((size_t)(n * kP + p) << 14) + y * kH + px] =
        (attf + atth + dpa) * (1.0f / 3.0f);

    // ---- edge messages: part-p threads compute edge p (p<5) ----
    constexpr int EA[5] = {0, 1, 2, 1, 4};
    constexpr int EB[5] = {1, 2, 3, 4, 5};
    if (p < 5) {
        const int a = EA[p], b = EB[p];
        float xa[kHD], xb[kHD];
        #pragma unroll
        for (int c = 0; c < kHD; ++c) {
            xa[c] = xpl[a * kHD + c][px];
            xb[c] = xpl[b * kHD + c][px];
        }
        #pragma unroll
        for (int d = 0; d < kHD; ++d) {
            const float* w = Wdp + (size_t)(p * kHD + d) * (2 * kHD);
            float t = 0.0f;
            #pragma unroll
            for (int c = 0; c < kHD; ++c) t += xa[c] * w[c];
            #pragma unroll
            for (int c = 0; c < kHD; ++c) t += xb[c] * w[kHD + c];
            dpl[p][d][px] = fmaxf(t, 0.0f);
        }
    }
    __syncthreads();

    // ---- gather messages into my part ----
    float xpp[kHD];
    #pragma unroll
    for (int c = 0; c < kHD; ++c) xpp[c] = 0.0f;
    #pragma unroll
    for (int e = 0; e < 5; ++e) {
        if (EA[e] == p || EB[e] == p) {             // wave-uniform
            const int other = EA[e] + EB[e] - p;
            const float s = 2.0f - dpal[other][px];
            #pragma unroll
            for (int c = 0; c < kHD; ++c) xpp[c] += s * dpl[e][c][px];
        }
    }

    // ---- update + store ----
    #pragma unroll
    for (int d = 0; d < kHD; ++d) {
        const float* w = Wup + (size_t)(p * kHD + d) * (4 * kHD);
        float a1 = 0.0f, a2 = 0.0f, a3 = 0.0f, a4 = 0.0f;
        #pragma unroll
        for (int c = 0; c < kHD; ++c) {
            a1 += xpv[c] * w[c];
            a2 += xfv[c] * w[kHD + c];
            a3 += xhv[c] * w[2 * kHD + c];
            a4 += xpp[c] * w[3 * kHD + c];
        }
        float upd = a1 + attf * a2 + atth * a3 + a4;
        upd = fmaxf(upd, 0.0f);
        const float o = fmaxf(xpv[d] + upd, 0.0f);
        out_xp[((size_t)((n * kP + p) * kHD + d) << 14) + y * kH + px] = o;
    }
}

extern "C" void kernel_launch(void* const* d_in, const int* in_sizes, int n_in,
                              void* d_out, int out_size, void* d_ws, size_t ws_size,
                              hipStream_t stream) {
    const float* xf   = (const float*)d_in[0];
    const float* xh0  = (const float*)d_in[1];
    const float* xh1  = (const float*)d_in[2];
    const float* xp   = (const float*)d_in[3];
    const float* Wf   = (const float*)d_in[4];
    const float* bfb  = (const float*)d_in[5];
    const float* Wh   = (const float*)d_in[6];
    const float* bhb  = (const float*)d_in[7];
    const float* Watt = (const float*)d_in[8];
    const float* batt = (const float*)d_in[9];
    const float* Wdp  = (const float*)d_in[10];
    const float* Wup  = (const float*)d_in[11];

    int N = out_size / ((kP * kHD + kP) * kH * kH);
    if (N <= 0) N = 32;

    float* out_xp  = (float*)d_out;
    float* out_att = out_xp + (size_t)N * kP * kHD * kH * kH;

    const int block = 768;                 // 6 parts x 128 px (one row)
    const int grid = N * kH;               // one row per block
    Part_Graph_51539607552364_kernel<<<grid, block, 0, stream>>>(
        xf, xh0, xh1, xp, Wf, bfb, Wh, bhb, Watt, batt, Wdp, Wup,
        out_xp, out_att);
}

// Round 11
// 304.067 us; speedup vs baseline: 1.3426x; 1.3426x over previous
//
#include <hip/hip_runtime.h>
#include <hip/hip_bf16.h>

constexpr int kHD  = 10;
constexpr int kP   = 6;
constexpr int kH   = 128;
constexpr int kHin = 64;
constexpr float kScale = 63.0f / 127.0f;

__device__ __forceinline__ float sigm(float v) {
    return 1.0f / (1.0f + __expf(-v));
}

// Block = 768 threads = 12 waves = 6 parts x 128 px (one full output row of
// one image). Thread (p, px): p = tid>>7, px = tid&127. Wave-uniform part ->
// all weight reads are scalar loads. xp/xh/xf staged in LDS (exact footprint);
// messages computed once per edge and exchanged via LDS.
// NOTE: no min-waves clause — (768,4) forced VGPR=64 and spilled ~300MB of
// scratch (R10). A bare 768 caps VGPR at 128 (schedulability) which fits the
// ~80-float live state without spill.
__global__ __launch_bounds__(768)
void Part_Graph_51539607552364_kernel(
    const float* __restrict__ xf,  const float* __restrict__ xh0,
    const float* __restrict__ xh1, const float* __restrict__ xp,
    const float* __restrict__ Wf,  const float* __restrict__ bfb,
    const float* __restrict__ Wh,  const float* __restrict__ bhb,
    const float* __restrict__ Watt, const float* __restrict__ batt,
    const float* __restrict__ Wdp, const float* __restrict__ Wup,
    float* __restrict__ out_xp,
    float* __restrict__ out_att)
{
    __shared__ float xpl[kP * kHD][kH];   // 30720 B  xp row tile
    __shared__ float xvl[2 * kHD][kHin];  //  5120 B  fy-blended xh source rows
    __shared__ float xfl[kHD][kHin];      //  2560 B  xf source row
    __shared__ float dpl[5][kHD][kH];     // 25600 B  edge messages
    __shared__ float dpal[kP][kH];        //  3072 B  dp_att       (total 67072)

    const int bid = blockIdx.x;
    const int n = bid >> 7;               // image
    const int y = bid & 127;              // output row

    int y0 = (int)((float)y * kScale); if (y0 > kHin - 2) y0 = kHin - 2;
    const float fy = (float)y * kScale - (float)y0;

    // ---- stage xp row: 60 planes x 128 cols ----
    for (int j = threadIdx.x; j < kP * kHD * kH; j += 768) {
        const int s = j >> 7, col = j & 127;
        xpl[s][col] = xp[((size_t)(n * kP * kHD + s) << 14) + y * kH + col];
    }
    // ---- stage xh rows y0,y0+1 blended by fy (block-uniform) ----
    for (int j = threadIdx.x; j < 2 * kHD * kHin; j += 768) {
        const int s = j >> 6, col = j & 63;          // s = map*10 + c
        const int m = s / kHD, c = s - m * kHD;
        const float* src = (m ? xh1 : xh0) +
                           ((size_t)((n * kHD + c) * kHin + y0) << 6) + col;
        const float r0 = src[0], r1 = src[kHin];
        xvl[s][col] = r0 + fy * (r1 - r0);
    }
    // ---- stage xf source row (y>>1) ----
    for (int j = threadIdx.x; j < kHD * kHin; j += 768) {
        const int c = j >> 6, col = j & 63;
        xfl[c][col] = xf[((size_t)((n * kHD + c) * kHin + (y >> 1)) << 6) + col];
    }
    __syncthreads();

    const int p  = threadIdx.x >> 7;      // part 0..5 (wave-uniform)
    const int px = threadIdx.x & 127;     // pixel in row

    // ---- per-thread inputs ----
    const float pxf_ = (float)px * kScale;
    int x0 = (int)pxf_; if (x0 > kHin - 2) x0 = kHin - 2;
    const float fx = pxf_ - (float)x0;
    const int m = (p >= 4) ? 1 : 0;

    float xpv[kHD], xhv[kHD], xfv[kHD];
    #pragma unroll
    for (int c = 0; c < kHD; ++c) {
        xpv[c] = xpl[p * kHD + c][px];
        const float* vr = &xvl[m * kHD + c][0];
        const float v0 = vr[x0], v1 = vr[x0 + 1];
        xhv[c] = v0 + fx * (v1 - v0);
        xfv[c] = xfl[c][px >> 1];
    }

    // ---- attentions (weights wave-uniform -> scalar loads) ----
    float af = bfb[p], ah = bhb[p], ad = batt[p];
    #pragma unroll
    for (int c = 0; c < kHD; ++c) {
        af += xfv[c] * Wf[p * 2 * kHD + c] + xpv[c] * Wf[p * 2 * kHD + kHD + c];
        ah += xhv[c] * Wh[p * 2 * kHD + c] + xpv[c] * Wh[p * 2 * kHD + kHD + c];
        ad += xpv[c] * Watt[p * kHD + c];
    }
    const float attf = sigm(af), atth = sigm(ah), dpa = sigm(ad);
    dpal[p][px] = dpa;
    out_att[((size_t)(n * kP + p) << 14) + y * kH + px] =
        (attf + atth + dpa) * (1.0f / 3.0f);

    // ---- edge messages: part-p threads compute edge p (p<5) ----
    constexpr int EA[5] = {0, 1, 2, 1, 4};
    constexpr int EB[5] = {1, 2, 3, 4, 5};
    if (p < 5) {
        const int a = EA[p], b = EB[p];
        float xa[kHD], xb[kHD];
        #pragma unroll
        for (int c = 0; c < kHD; ++c) {
            xa[c] = xpl[a * kHD + c][px];
            xb[c] = xpl[b * kHD + c][px];
        }
        #pragma unroll
        for (int d = 0; d < kHD; ++d) {
            const float* w = Wdp + (size_t)(p * kHD + d) * (2 * kHD);
            float t = 0.0f;
            #pragma unroll
            for (int c = 0; c < kHD; ++c) t += xa[c] * w[c];
            #pragma unroll
            for (int c = 0; c < kHD; ++c) t += xb[c] * w[kHD + c];
            dpl[p][d][px] = fmaxf(t, 0.0f);
        }
    }
    __syncthreads();

    // ---- gather messages into my part ----
    float xpp[kHD];
    #pragma unroll
    for (int c = 0; c < kHD; ++c) xpp[c] = 0.0f;
    #pragma unroll
    for (int e = 0; e < 5; ++e) {
        if (EA[e] == p || EB[e] == p) {             // wave-uniform
            const int other = EA[e] + EB[e] - p;
            const float s = 2.0f - dpal[other][px];
            #pragma unroll
            for (int c = 0; c < kHD; ++c) xpp[c] += s * dpl[e][c][px];
        }
    }

    // ---- update + store ----
    #pragma unroll
    for (int d = 0; d < kHD; ++d) {
        const float* w = Wup + (size_t)(p * kHD + d) * (4 * kHD);
        float a1 = 0.0f, a2 = 0.0f, a3 = 0.0f, a4 = 0.0f;
        #pragma unroll
        for (int c = 0; c < kHD; ++c) {
            a1 += xpv[c] * w[c];
            a2 += xfv[c] * w[kHD + c];
            a3 += xhv[c] * w[2 * kHD + c];
            a4 += xpp[c] * w[3 * kHD + c];
        }
        float upd = a1 + attf * a2 + atth * a3 + a4;
        upd = fmaxf(upd, 0.0f);
        const float o = fmaxf(xpv[d] + upd, 0.0f);
        out_xp[((size_t)((n * kP + p) * kHD + d) << 14) + y * kH + px] = o;
    }
}

extern "C" void kernel_launch(void* const* d_in, const int* in_sizes, int n_in,
                              void* d_out, int out_size, void* d_ws, size_t ws_size,
                              hipStream_t stream) {
    const float* xf   = (const float*)d_in[0];
    const float* xh0  = (const float*)d_in[1];
    const float* xh1  = (const float*)d_in[2];
    const float* xp   = (const float*)d_in[3];
    const float* Wf   = (const float*)d_in[4];
    const float* bfb  = (const float*)d_in[5];
    const float* Wh   = (const float*)d_in[6];
    const float* bhb  = (const float*)d_in[7];
    const float* Watt = (const float*)d_in[8];
    const float* batt = (const float*)d_in[9];
    const float* Wdp  = (const float*)d_in[10];
    const float* Wup  = (const float*)d_in[11];

    int N = out_size / ((kP * kHD + kP) * kH * kH);
    if (N <= 0) N = 32;

    float* out_xp  = (float*)d_out;
    float* out_att = out_xp + (size_t)N * kP * kHD * kH * kH;

    const int block = 768;                 // 6 parts x 128 px (one row)
    const int grid = N * kH;               // one row per block
    Part_Graph_51539607552364_kernel<<<grid, block, 0, stream>>>(
        xf, xh0, xh1, xp, Wf, bfb, Wh, bhb, Watt, batt, Wdp, Wup,
        out_xp, out_att);
}

// Round 12
// 147.216 us; speedup vs baseline: 2.7731x; 2.0655x over previous
//
#include <hip/hip_runtime.h>
#include <hip/hip_bf16.h>

constexpr int kHD  = 10;   // hidden dim
constexpr int kP   = 6;    // parts
constexpr int kNE  = 5;    // edges
constexpr int kH   = 128;  // part-map H=W
constexpr int kHin = 64;   // coarse-map H=W
constexpr int kSeg = 70;   // 60 xh row-segments + 10 xf row-segments
constexpr int kSegPad = 72; // padded to a multiple of 4 for 16B DMA groups

__device__ __forceinline__ float sigm(float v) {
    return 1.0f / (1.0f + __expf(-v));
}

// R6 structure (best so far: 138.6us) with the VMEM latency consolidated:
//  - staging via global_load_lds width=16 (4 segments/instr, no VGPR
//    round-trip, no per-iteration vmcnt drain)
//  - all 60 xp loads hoisted ABOVE the barrier so the single barrier drain
//    covers staging DMA + xp loads in one concentrated wait.
__global__ __launch_bounds__(256, 2)
void Part_Graph_51539607552364_kernel(
    const float* __restrict__ xf,  const float* __restrict__ xh0,
    const float* __restrict__ xh1, const float* __restrict__ xp,
    const float* __restrict__ Wf,  const float* __restrict__ bfb,
    const float* __restrict__ Wh,  const float* __restrict__ bhb,
    const float* __restrict__ Watt, const float* __restrict__ batt,
    const float* __restrict__ Wdp, const float* __restrict__ Wup,
    float* __restrict__ out_xp,
    float* __restrict__ out_att)
{
    __shared__ float stage[kSegPad * kHin];   // 72*64*4 = 18432 B

    const int bid = blockIdx.x;
    const int n   = bid >> 6;           // 64 blocks per image
    const int R   = bid & 63;           // row-pair index; rows yA=2R, yA+1
    const int yA  = R * 2;

    const float scale = 63.0f / 127.0f;
    int ry0 = (int)((float)yA * scale);
    ry0 = ry0 > (kHin - 2) ? (kHin - 2) : ry0;

    // ---- PHASE 1a: issue staging DMA (global -> LDS, 16B/lane) ----
    // group g covers segments 4g..4g+3; lane l writes LDS bytes [l*16, l*16+16)
    // at base stage[g*256], i.e. segment 4g + (l>>4), floats (l&15)*4 .. +3.
    {
        const int wv = threadIdx.x >> 6;       // wave 0..3
        const int l  = threadIdx.x & 63;       // lane
        for (int g = wv; g < kSegPad / 4; g += 4) {
            int seg = g * 4 + (l >> 4);
            if (seg > kSeg - 1) seg = kSeg - 1;          // pad lanes clamp
            const int col4 = (l & 15) * 4;
            const float* rowp;
            if (seg < 60) {
                const int map = seg / 30, rem = seg % 30;
                const int ch = rem / 3, r3 = rem % 3;
                int srow = ry0 + r3;
                srow = srow > (kHin - 1) ? (kHin - 1) : srow;
                rowp = (map ? xh1 : xh0) +
                       ((size_t)(n * kHD + ch) * kHin + srow) * kHin;
            } else {
                const int ch = seg - 60;
                rowp = xf + ((size_t)(n * kHD + ch) * kHin + R) * kHin;
            }
            const float* gp = rowp + col4;
            __builtin_amdgcn_global_load_lds(
                (const __attribute__((address_space(1))) void*)gp,
                (__attribute__((address_space(3))) void*)(&stage[g * 256]),
                16, 0, 0);
        }
    }

    // ---- PHASE 1b: issue all 60 xp loads (drained by the same barrier) ----
    const int ly = threadIdx.x >> 7;          // 0/1 within the row pair
    const int xc = threadIdx.x & (kH - 1);
    const int yc = yA + ly;

    float xpv[kP][kHD];
    {
        const float* b = xp + (size_t)(n * kP * kHD) * (kH * kH) + yc * kH + xc;
        #pragma unroll
        for (int p = 0; p < kP; ++p)
            #pragma unroll
            for (int c = 0; c < kHD; ++c)
                xpv[p][c] = b[(size_t)(p * kHD + c) * (kH * kH)];
    }

    __syncthreads();   // single concentrated drain: DMA + xp loads

    // ---- PHASE 2: window reads from LDS ----
    const float py = (float)yc * scale;
    int y0 = (int)py; y0 = y0 > (kHin - 2) ? (kHin - 2) : y0;
    const float fy = py - (float)y0;
    const int d0 = y0 - ry0;                  // 0 or 1
    const float pxf_ = (float)xc * scale;
    int x0 = (int)pxf_; x0 = x0 > (kHin - 2) ? (kHin - 2) : x0;
    const float fx = pxf_ - (float)x0;
    const float w00 = (1.0f - fy) * (1.0f - fx);
    const float w01 = (1.0f - fy) * fx;
    const float w10 = fy * (1.0f - fx);
    const float w11 = fy * fx;

    float xh0v[kHD], xh1v[kHD];
    #pragma unroll
    for (int c = 0; c < kHD; ++c) {
        const float* r0 = &stage[(c * 3 + d0) * kHin];
        xh0v[c] = r0[x0] * w00 + r0[x0 + 1] * w01 +
                  r0[kHin + x0] * w10 + r0[kHin + x0 + 1] * w11;
        const float* r1 = &stage[(30 + c * 3 + d0) * kHin];
        xh1v[c] = r1[x0] * w00 + r1[x0 + 1] * w01 +
                  r1[kHin + x0] * w10 + r1[kHin + x0 + 1] * w11;
    }
    const int sx = xc >> 1;
    float xfv[kHD];
    #pragma unroll
    for (int c = 0; c < kHD; ++c) xfv[c] = stage[(60 + c) * kHin + sx];

    // ---- PHASE 3: attentions ----
    float attf[kP], atth[kP], dpa[kP];
    #pragma unroll
    for (int p = 0; p < kP; ++p) {
        float af = bfb[p];
        float ah = bhb[p];
        float ad = batt[p];
        #pragma unroll
        for (int c = 0; c < kHD; ++c) {
            const float xhc = (p < 4) ? xh0v[c] : xh1v[c];
            af += xfv[c]    * Wf[p * 2 * kHD + c];
            af += xpv[p][c] * Wf[p * 2 * kHD + kHD + c];
            ah += xhc       * Wh[p * 2 * kHD + c];
            ah += xpv[p][c] * Wh[p * 2 * kHD + kHD + c];
            ad += xpv[p][c] * Watt[p * kHD + c];
        }
        attf[p] = sigm(af);
        atth[p] = sigm(ah);
        dpa[p]  = sigm(ad);
    }

    const size_t pixoff = (size_t)yc * kH + xc;
    #pragma unroll
    for (int p = 0; p < kP; ++p) {
        const float ap = (attf[p] + atth[p] + dpa[p]) * (1.0f / 3.0f);
        out_att[(size_t)(n * kP + p) * (kH * kH) + pixoff] = ap;
    }

    // ---- PHASE 4: edge messages -> xpp ----
    float xpp[kP][kHD];
    #pragma unroll
    for (int p = 0; p < kP; ++p)
        #pragma unroll
        for (int c = 0; c < kHD; ++c) xpp[p][c] = 0.0f;

    constexpr int EA[kNE] = {0, 1, 2, 1, 4};
    constexpr int EB[kNE] = {1, 2, 3, 4, 5};
    #pragma unroll
    for (int e = 0; e < kNE; ++e) {
        const int a = EA[e], b = EB[e];
        const float sa = 2.0f - dpa[a];
        const float sb = 2.0f - dpa[b];
        #pragma unroll
        for (int d = 0; d < kHD; ++d) {
            const float* w = Wdp + (size_t)(e * kHD + d) * (2 * kHD);
            float t = 0.0f;
            #pragma unroll
            for (int c = 0; c < kHD; ++c) t += xpv[a][c] * w[c];
            #pragma unroll
            for (int c = 0; c < kHD; ++c) t += xpv[b][c] * w[kHD + c];
            t = fmaxf(t, 0.0f);
            xpp[b][d] += t * sa;
            xpp[a][d] += t * sb;
        }
    }

    // ---- PHASE 5: update + stores ----
    #pragma unroll
    for (int p = 0; p < kP; ++p) {
        #pragma unroll
        for (int d = 0; d < kHD; ++d) {
            const float* w = Wup + (size_t)(p * kHD + d) * (4 * kHD);
            float a1 = 0.0f, a2 = 0.0f, a3 = 0.0f, a4 = 0.0f;
            #pragma unroll
            for (int c = 0; c < kHD; ++c) {
                const float xhc = (p < 4) ? xh0v[c] : xh1v[c];
                a1 += xpv[p][c] * w[c];
                a2 += xfv[c]    * w[kHD + c];
                a3 += xhc       * w[2 * kHD + c];
                a4 += xpp[p][c] * w[3 * kHD + c];
            }
            float upd = a1 + attf[p] * a2 + atth[p] * a3 + a4;
            upd = fmaxf(upd, 0.0f);
            float o = xpv[p][d] + upd;
            o = fmaxf(o, 0.0f);
            out_xp[(size_t)(n * kP * kHD + p * kHD + d) * (kH * kH) + pixoff] = o;
        }
    }
}

extern "C" void kernel_launch(void* const* d_in, const int* in_sizes, int n_in,
                              void* d_out, int out_size, void* d_ws, size_t ws_size,
                              hipStream_t stream) {
    const float* xf   = (const float*)d_in[0];
    const float* xh0  = (const float*)d_in[1];
    const float* xh1  = (const float*)d_in[2];
    const float* xp   = (const float*)d_in[3];
    const float* Wf   = (const float*)d_in[4];
    const float* bfb  = (const float*)d_in[5];
    const float* Wh   = (const float*)d_in[6];
    const float* bhb  = (const float*)d_in[7];
    const float* Watt = (const float*)d_in[8];
    const float* batt = (const float*)d_in[9];
    const float* Wdp  = (const float*)d_in[10];
    const float* Wup  = (const float*)d_in[11];

    int N = out_size / ((kP * kHD + kP) * kH * kH);
    if (N <= 0) N = 32;
    const int npix = N * kH * kH;

    float* out_xp  = (float*)d_out;
    float* out_att = out_xp + (size_t)N * kP * kHD * kH * kH;

    const int block = 256;                 // 2 rows per block
    const int grid = npix / block;         // 64 blocks per image
    Part_Graph_51539607552364_kernel<<<grid, block, 0, stream>>>(
        xf, xh0, xh1, xp, Wf, bfb, Wh, bhb, Watt, batt, Wdp, Wup,
        out_xp, out_att);
}

// Round 13
// 97.400 us; speedup vs baseline: 4.1915x; 1.5115x over previous
//
#include <hip/hip_runtime.h>
#include <hip/hip_bf16.h>

typedef _Float16 half2v __attribute__((ext_vector_type(2)));

constexpr int kHD  = 10;
constexpr int kP   = 6;
constexpr int kNE  = 5;
constexpr int kH   = 128;
constexpr int kHin = 64;
constexpr int kSeg = 70;   // 60 xh row-segments + 10 xf row-segments

// packed-weight layout in d_ws (half2 pairs)
constexpr int WF2  = 0;     // 60  : Wf  [p][20]
constexpr int WH2  = 60;    // 60  : Wh  [p][20]
constexpr int WATT2= 120;   // 30  : Watt[p][10]
constexpr int WDP2 = 150;   // 500 : Wdp [e][10][20]
constexpr int WUP2 = 650;   // 1200: Wup [p][10][40]
constexpr int NPAIR= 1850;

__device__ __forceinline__ float sigm(float v) {
    return 1.0f / (1.0f + __expf(-v));
}
__device__ __forceinline__ half2v pk(float a, float b) {
    half2v h; h[0] = (_Float16)a; h[1] = (_Float16)b; return h;
}
__device__ __forceinline__ float dot2(half2v a, half2v b, float c) {
    return __builtin_amdgcn_fdot2(a, b, c, false);
}

__global__ __launch_bounds__(256)
void prepack_weights(const float* __restrict__ Wf,  const float* __restrict__ Wh,
                     const float* __restrict__ Watt, const float* __restrict__ Wdp,
                     const float* __restrict__ Wup, half2v* __restrict__ out)
{
    const int i = blockIdx.x * 256 + threadIdx.x;
    if (i >= NPAIR) return;
    const float* src; int k;
    if      (i < WH2)   { src = Wf;   k = i; }
    else if (i < WATT2) { src = Wh;   k = i - WH2; }
    else if (i < WDP2)  { src = Watt; k = i - WATT2; }
    else if (i < WUP2)  { src = Wdp;  k = i - WDP2; }
    else                { src = Wup;  k = i - WUP2; }
    out[i] = pk(src[2 * k], src[2 * k + 1]);
}

// R6 skeleton (best anchor, 138.6us) with all channel dot-products converted
// to v_dot2_f32_f16 (2 MACs/instr, f32 accumulate) against pre-packed half2
// weights in d_ws. Halves both VALU FMA count and the scalar weight stream.
__global__ __launch_bounds__(256, 2)
void Part_Graph_51539607552364_kernel(
    const float* __restrict__ xf,  const float* __restrict__ xh0,
    const float* __restrict__ xh1, const float* __restrict__ xp,
    const half2v* __restrict__ w2,
    const float* __restrict__ bfb, const float* __restrict__ bhb,
    const float* __restrict__ batt,
    float* __restrict__ out_xp,
    float* __restrict__ out_att)
{
    __shared__ float stage[kSeg * kHin];   // 17920 B

    const int bid = blockIdx.x;
    const int n   = bid >> 6;           // 64 blocks per image
    const int R   = bid & 63;           // row-pair index; rows yA=2R, yA+1
    const int yA  = R * 2;

    const float scale = 63.0f / 127.0f;
    int ry0 = (int)((float)yA * scale);
    ry0 = ry0 > (kHin - 2) ? (kHin - 2) : ry0;

    // ---- cooperative staging (R6 verbatim) ----
    {
        const int wv = threadIdx.x >> 6;
        const int l  = threadIdx.x & 63;
        for (int s = wv; s < kSeg; s += 4) {
            const float* src;
            if (s < 60) {
                const int map = s / 30, rem = s % 30;
                const int ch = rem / 3, r3 = rem % 3;
                int srow = ry0 + r3;
                srow = srow > (kHin - 1) ? (kHin - 1) : srow;
                src = (map ? xh1 : xh0) +
                      ((size_t)(n * kHD + ch) * kHin + srow) * kHin;
            } else {
                const int ch = s - 60;
                src = xf + ((size_t)(n * kHD + ch) * kHin + R) * kHin;
            }
            stage[s * kHin + l] = src[l];
        }
    }
    __syncthreads();

    const int ly = threadIdx.x >> 7;
    const int xc = threadIdx.x & (kH - 1);
    const int yc = yA + ly;

    // ---- bilinear coords ----
    const float py = (float)yc * scale;
    int y0 = (int)py; y0 = y0 > (kHin - 2) ? (kHin - 2) : y0;
    const float fy = py - (float)y0;
    const int d0 = y0 - ry0;
    const float pxf_ = (float)xc * scale;
    int x0 = (int)pxf_; x0 = x0 > (kHin - 2) ? (kHin - 2) : x0;
    const float fx = pxf_ - (float)x0;
    const float w00 = (1.0f - fy) * (1.0f - fx);
    const float w01 = (1.0f - fy) * fx;
    const float w10 = fy * (1.0f - fx);
    const float w11 = fy * fx;

    // ---- windows from LDS -> packed half2 ----
    half2v xh0v2[5], xh1v2[5], xfv2[5];
    const int sx = xc >> 1;
    #pragma unroll
    for (int j = 0; j < 5; ++j) {
        float v[2], u[2], f[2];
        #pragma unroll
        for (int t = 0; t < 2; ++t) {
            const int c = 2 * j + t;
            const float* r0 = &stage[(c * 3 + d0) * kHin];
            v[t] = r0[x0] * w00 + r0[x0 + 1] * w01 +
                   r0[kHin + x0] * w10 + r0[kHin + x0 + 1] * w11;
            const float* r1 = &stage[(30 + c * 3 + d0) * kHin];
            u[t] = r1[x0] * w00 + r1[x0 + 1] * w01 +
                   r1[kHin + x0] * w10 + r1[kHin + x0 + 1] * w11;
            f[t] = stage[(60 + c) * kHin + sx];
        }
        xh0v2[j] = pk(v[0], v[1]);
        xh1v2[j] = pk(u[0], u[1]);
        xfv2[j]  = pk(f[0], f[1]);
    }

    // ---- xp loads -> packed half2 ----
    half2v xpv2[kP][5];
    {
        const float* b = xp + (size_t)(n * kP * kHD) * (kH * kH) + yc * kH + xc;
        #pragma unroll
        for (int p = 0; p < kP; ++p)
            #pragma unroll
            for (int j = 0; j < 5; ++j) {
                const float lo = b[(size_t)(p * kHD + 2 * j)     * (kH * kH)];
                const float hi = b[(size_t)(p * kHD + 2 * j + 1) * (kH * kH)];
                xpv2[p][j] = pk(lo, hi);
            }
    }

    // ---- attentions via fdot2 ----
    float attf[kP], atth[kP], dpa[kP];
    #pragma unroll
    for (int p = 0; p < kP; ++p) {
        float af = bfb[p], ah = bhb[p], ad = batt[p];
        #pragma unroll
        for (int j = 0; j < 5; ++j) {
            const half2v xh2 = (p < 4) ? xh0v2[j] : xh1v2[j];
            af = dot2(xfv2[j],    w2[WF2 + p * 10 + j],     af);
            af = dot2(xpv2[p][j], w2[WF2 + p * 10 + 5 + j], af);
            ah = dot2(xh2,        w2[WH2 + p * 10 + j],     ah);
            ah = dot2(xpv2[p][j], w2[WH2 + p * 10 + 5 + j], ah);
            ad = dot2(xpv2[p][j], w2[WATT2 + p * 5 + j],    ad);
        }
        attf[p] = sigm(af);
        atth[p] = sigm(ah);
        dpa[p]  = sigm(ad);
    }

    const size_t pixoff = (size_t)yc * kH + xc;
    #pragma unroll
    for (int p = 0; p < kP; ++p) {
        const float ap = (attf[p] + atth[p] + dpa[p]) * (1.0f / 3.0f);
        out_att[(size_t)(n * kP + p) * (kH * kH) + pixoff] = ap;
    }

    // ---- edge messages via fdot2 (f32 xpp accumulators) ----
    float xpp[kP][kHD];
    #pragma unroll
    for (int p = 0; p < kP; ++p)
        #pragma unroll
        for (int c = 0; c < kHD; ++c) xpp[p][c] = 0.0f;

    constexpr int EA[kNE] = {0, 1, 2, 1, 4};
    constexpr int EB[kNE] = {1, 2, 3, 4, 5};
    #pragma unroll
    for (int e = 0; e < kNE; ++e) {
        const int a = EA[e], b = EB[e];
        const float sa = 2.0f - dpa[a];
        const float sb = 2.0f - dpa[b];
        #pragma unroll
        for (int d = 0; d < kHD; ++d) {
            float t = 0.0f;
            #pragma unroll
            for (int j = 0; j < 5; ++j) {
                t = dot2(xpv2[a][j], w2[WDP2 + (e * 10 + d) * 10 + j],     t);
                t = dot2(xpv2[b][j], w2[WDP2 + (e * 10 + d) * 10 + 5 + j], t);
            }
            t = fmaxf(t, 0.0f);
            xpp[b][d] += t * sa;
            xpp[a][d] += t * sb;
        }
    }
    // pack xpp -> half2 (frees 60 f32 -> 30 packed)
    half2v xpp2[kP][5];
    #pragma unroll
    for (int p = 0; p < kP; ++p)
        #pragma unroll
        for (int j = 0; j < 5; ++j)
            xpp2[p][j] = pk(xpp[p][2 * j], xpp[p][2 * j + 1]);

    // ---- update via fdot2 + stores ----
    #pragma unroll
    for (int p = 0; p < kP; ++p) {
        #pragma unroll
        for (int d = 0; d < kHD; ++d) {
            const int wb = WUP2 + (p * 10 + d) * 20;
            float a1 = 0.0f, a2 = 0.0f, a3 = 0.0f, a4 = 0.0f;
            #pragma unroll
            for (int j = 0; j < 5; ++j) {
                const half2v xh2 = (p < 4) ? xh0v2[j] : xh1v2[j];
                a1 = dot2(xpv2[p][j], w2[wb + j],      a1);
                a2 = dot2(xfv2[j],    w2[wb + 5 + j],  a2);
                a3 = dot2(xh2,        w2[wb + 10 + j], a3);
                a4 = dot2(xpp2[p][j], w2[wb + 15 + j], a4);
            }
            float upd = a1 + attf[p] * a2 + atth[p] * a3 + a4;
            upd = fmaxf(upd, 0.0f);
            const float xpd = (float)xpv2[p][d >> 1][d & 1];
            const float o = fmaxf(xpd + upd, 0.0f);
            out_xp[(size_t)(n * kP * kHD + p * kHD + d) * (kH * kH) + pixoff] = o;
        }
    }
}

extern "C" void kernel_launch(void* const* d_in, const int* in_sizes, int n_in,
                              void* d_out, int out_size, void* d_ws, size_t ws_size,
                              hipStream_t stream) {
    const float* xf   = (const float*)d_in[0];
    const float* xh0  = (const float*)d_in[1];
    const float* xh1  = (const float*)d_in[2];
    const float* xp   = (const float*)d_in[3];
    const float* Wf   = (const float*)d_in[4];
    const float* bfb  = (const float*)d_in[5];
    const float* Wh   = (const float*)d_in[6];
    const float* bhb  = (const float*)d_in[7];
    const float* Watt = (const float*)d_in[8];
    const float* batt = (const float*)d_in[9];
    const float* Wdp  = (const float*)d_in[10];
    const float* Wup  = (const float*)d_in[11];

    int N = out_size / ((kP * kHD + kP) * kH * kH);
    if (N <= 0) N = 32;
    const int npix = N * kH * kH;

    float* out_xp  = (float*)d_out;
    float* out_att = out_xp + (size_t)N * kP * kHD * kH * kH;
    half2v* w2 = (half2v*)d_ws;

    prepack_weights<<<(NPAIR + 255) / 256, 256, 0, stream>>>(
        Wf, Wh, Watt, Wdp, Wup, w2);

    const int block = 256;
    const int grid = npix / block;
    Part_Graph_51539607552364_kernel<<<grid, block, 0, stream>>>(
        xf, xh0, xh1, xp, w2, bfb, bhb, batt, out_xp, out_att);
}